// Round 1
// baseline (1527.895 us; speedup 1.0000x reference)
//
#include <hip/hip_runtime.h>
#include <cstdint>

typedef unsigned int u32;
typedef unsigned short u16;
typedef __bf16 bf16x8 __attribute__((ext_vector_type(8)));
typedef float f32x4 __attribute__((ext_vector_type(4)));

#define NTOK 4096
#define HDIM 2048
#define FMOE 1024
#define FSH  2048
#define NEXP 16

__device__ __forceinline__ u16 f2bf(float f) {
  u32 u = __float_as_uint(f);
  u32 r = (u + 0x7fffu + ((u >> 16) & 1u)) >> 16;
  return (u16)r;
}
__device__ __forceinline__ float bf2f(u16 h) {
  return __uint_as_float(((u32)h) << 16);
}

__device__ __forceinline__ void gld_lds16(const void* g, void* l) {
  __builtin_amdgcn_global_load_lds(
      (const __attribute__((address_space(1))) u32*)g,
      (__attribute__((address_space(3))) u32*)l, 16, 0, 0);
}

// ---------------- fp32 -> bf16 conversion (vectorized x4) ----------------
__global__ void cvt_bf16(const float* __restrict__ in, u16* __restrict__ out, long n4) {
  long i = (long)blockIdx.x * blockDim.x + threadIdx.x;
  if (i < n4) {
    float4 v = ((const float4*)in)[i];
    ushort4 o;
    o.x = f2bf(v.x); o.y = f2bf(v.y); o.z = f2bf(v.z); o.w = f2bf(v.w);
    ((ushort4*)out)[i] = o;
  }
}

// convert gate_w + up_w into concatenated per-expert layout GU[e][0:F]=gate, GU[e][F:2F]=up
__global__ void cvt_pair_moe(const float* __restrict__ g, const float* __restrict__ u,
                             u16* __restrict__ dst) {
  int e = blockIdx.z;
  const long n4 = (long)FMOE * HDIM / 4;
  long i = (long)blockIdx.x * blockDim.x + threadIdx.x;
  const float4* gs = (const float4*)(g + (long)e * FMOE * HDIM);
  const float4* us = (const float4*)(u + (long)e * FMOE * HDIM);
  ushort4* d = (ushort4*)(dst + (long)e * 2 * FMOE * HDIM);
  float4 v = gs[i];
  ushort4 o;
  o.x = f2bf(v.x); o.y = f2bf(v.y); o.z = f2bf(v.z); o.w = f2bf(v.w);
  d[i] = o;
  v = us[i];
  o.x = f2bf(v.x); o.y = f2bf(v.y); o.z = f2bf(v.z); o.w = f2bf(v.w);
  d[n4 + i] = o;
}

// ---------------- routing: gate weights staged in LDS, one wave per token ----------------
__global__ __launch_bounds__(256) void routing_kernel(
    const float* __restrict__ hidden, const float* __restrict__ gw,
    const float* __restrict__ bias, int* __restrict__ topk_idx,
    float* __restrict__ topk_w, int* __restrict__ counts) {
  __shared__ float gws[8 * HDIM];  // 64 KB: 8 experts per pass
  int tid = threadIdx.x, lane = tid & 63, wv = tid >> 6;
  int t = blockIdx.x * 4 + wv;
  float acc[NEXP];
#pragma unroll
  for (int n = 0; n < NEXP; ++n) acc[n] = 0.f;
  const float4* h4 = (const float4*)(hidden + (long)t * HDIM);

  for (int half = 0; half < 2; ++half) {
    for (int i = tid; i < 8 * HDIM / 4; i += 256)
      ((float4*)gws)[i] = ((const float4*)(gw + half * 8 * HDIM))[i];
    __syncthreads();
#pragma unroll
    for (int j0 = 0; j0 < HDIM / 4; j0 += 64) {
      int j = j0 + lane;
      float4 hv = h4[j];
#pragma unroll
      for (int e = 0; e < 8; ++e) {
        float4 g = ((const float4*)gws)[e * (HDIM / 4) + j];
        acc[half * 8 + e] += hv.x * g.x + hv.y * g.y + hv.z * g.z + hv.w * g.w;
      }
    }
    __syncthreads();
  }
#pragma unroll
  for (int n = 0; n < NEXP; ++n) {
    float v = acc[n];
    for (int m = 32; m; m >>= 1) v += __shfl_xor(v, m);
    acc[n] = v;
  }
  if (lane == 0) {
    float sc[NEXP], scb[NEXP];
#pragma unroll
    for (int n = 0; n < NEXP; ++n) {
      sc[n] = 1.f / (1.f + expf(-acc[n]));
      scb[n] = sc[n] + bias[n];
    }
    float gs[4];
#pragma unroll
    for (int g = 0; g < 4; ++g) {
      float m1 = -1e30f, m2 = -1e30f;
#pragma unroll
      for (int j = 0; j < 4; ++j) {
        float v = scb[4 * g + j];
        if (v > m1) { m2 = m1; m1 = v; } else if (v > m2) { m2 = v; }
      }
      gs[g] = m1 + m2;
    }
    int g1 = -1, g2 = -1;
    { float b = -1e30f; for (int g = 0; g < 4; ++g) if (gs[g] > b) { b = gs[g]; g1 = g; } }
    { float b = -1e30f; for (int g = 0; g < 4; ++g) if (g != g1 && gs[g] > b) { b = gs[g]; g2 = g; } }
    bool used[NEXP];
#pragma unroll
    for (int n = 0; n < NEXP; ++n) used[n] = false;
    int sel[4]; float wts[4]; float s = 0.f;
    for (int k = 0; k < 4; ++k) {
      float b = -1e30f; int bi = 0;
      for (int n = 0; n < NEXP; ++n) {
        int g = n >> 2;
        if ((g == g1 || g == g2) && !used[n] && scb[n] > b) { b = scb[n]; bi = n; }
      }
      used[bi] = true; sel[k] = bi; wts[k] = sc[bi]; s += sc[bi];
    }
    float inv = 2.5f / (s + 1e-20f);
    for (int k = 0; k < 4; ++k) {
      topk_idx[t * 4 + k] = sel[k];
      topk_w[t * 4 + k] = wts[k] * inv;
      atomicAdd(&counts[sel[k]], 1);
    }
  }
}

// ---------------- prefix over 16 counts ----------------
__global__ void prefix16(const int* __restrict__ counts, int* __restrict__ offs) {
  if (threadIdx.x == 0) {
    int s = 0;
    for (int e = 0; e < NEXP; ++e) { offs[e] = s; s += counts[e]; }
    offs[NEXP] = s;
  }
}

// ---------------- deterministic ordered compaction + slot map ----------------
__global__ void fill_lists(const int* __restrict__ topk_idx,
                           const int* __restrict__ offs, int* __restrict__ ltok,
                           int* __restrict__ slotmap) {
  int e = blockIdx.x;
  int tid = threadIdx.x, lane = tid & 63, wv = tid >> 6;
  __shared__ int cursor;
  __shared__ int wcnt[4];
  if (tid == 0) cursor = offs[e];
  __syncthreads();
  for (int base = 0; base < NTOK; base += 256) {
    int t = base + tid;
    int flag = 0, kk = 0;
#pragma unroll
    for (int k = 0; k < 4; ++k) {
      if (topk_idx[t * 4 + k] == e) { flag = 1; kk = k; }
    }
    unsigned long long b = __ballot(flag);
    if (lane == 0) wcnt[wv] = __popcll(b);
    __syncthreads();
    int pre = 0;
    for (int i = 0; i < wv; ++i) pre += wcnt[i];
    int pos = cursor + pre + __popcll(b & ((1ull << lane) - 1ull));
    if (flag) { ltok[pos] = t; slotmap[t * 4 + kk] = pos; }
    __syncthreads();
    if (tid == 0) cursor += wcnt[0] + wcnt[1] + wcnt[2] + wcnt[3];
    __syncthreads();
  }
}

// ---------------- in-place paired silu ----------------
template <int F>
__global__ void silu_mul_pair(u16* __restrict__ gu, const int* __restrict__ nrows_ptr,
                              int nrows_static) {
  int rows = nrows_ptr ? *nrows_ptr : nrows_static;
  long total4 = (long)rows * (F / 4);
  long i = (long)blockIdx.x * blockDim.x + threadIdx.x;
  if (i < total4) {
    long row = i / (F / 4);
    int f4 = (int)(i - row * (F / 4));
    ushort4* rowp = (ushort4*)(gu + row * 2 * F);
    ushort4 gv = rowp[f4];
    ushort4 uv = rowp[F / 4 + f4];
    float gf, uf, sv;
    ushort4 o;
    gf = bf2f(gv.x); uf = bf2f(uv.x); sv = gf / (1.f + __expf(-gf)); o.x = f2bf(sv * uf);
    gf = bf2f(gv.y); uf = bf2f(uv.y); sv = gf / (1.f + __expf(-gf)); o.y = f2bf(sv * uf);
    gf = bf2f(gv.z); uf = bf2f(uv.z); sv = gf / (1.f + __expf(-gf)); o.z = f2bf(sv * uf);
    gf = bf2f(gv.w); uf = bf2f(uv.w); sv = gf / (1.f + __expf(-gf)); o.w = f2bf(sv * uf);
    rowp[f4] = o;
  }
}

// ---------------- final reduce ----------------
__global__ void reduce_out(const u16* __restrict__ SY, const u16* __restrict__ Y,
                           const int* __restrict__ slotmap, const float* __restrict__ tkw,
                           float* __restrict__ out) {
  long i = (long)blockIdx.x * blockDim.x + threadIdx.x;  // over NTOK*HDIM/4
  int t = (int)(i >> 9);       // HDIM/4 = 512
  int c4 = (int)(i & 511);
  ushort4 s = ((const ushort4*)SY)[i];
  float4 o;
  o.x = bf2f(s.x); o.y = bf2f(s.y); o.z = bf2f(s.z); o.w = bf2f(s.w);
#pragma unroll
  for (int k = 0; k < 4; ++k) {
    int sl = slotmap[t * 4 + k];
    float w = tkw[t * 4 + k];
    ushort4 y = ((const ushort4*)Y)[(long)sl * 512 + c4];
    o.x += w * bf2f(y.x);
    o.y += w * bf2f(y.y);
    o.z += w * bf2f(y.z);
    o.w += w * bf2f(y.w);
  }
  ((float4*)out)[i] = o;
}

// ================= 256x256 bf16 GEMM-BT, 8-phase counted-vmcnt schedule =================
// 512 thr = 8 waves (2M x 4N); per-wave 128x64 out; BK=64; 128 KiB LDS (2 bufs x [A 256x64 | B 256x64]).
// LDS regions (u16): buf p at p*32768; A half h at +h*8192; B half h at +16384+h*8192.
// Swizzle: 8-elem col-chunk ^= (row&7), applied on the global SOURCE (write side stays
// linear for global_load_lds) and on the ds_read address (rule #21: both-sides-or-neither).
#define LGKM0 asm volatile("s_waitcnt lgkmcnt(0)" ::: "memory")
#define VMC6  asm volatile("s_waitcnt vmcnt(6)" ::: "memory")
#define VMC0  asm volatile("s_waitcnt vmcnt(0)" ::: "memory")
__device__ __forceinline__ void bar() {
  asm volatile("" ::: "memory");
  __builtin_amdgcn_s_barrier();
  asm volatile("" ::: "memory");
}

__global__ __launch_bounds__(512, 2) void gemm256(
    const u16* __restrict__ A, const u16* __restrict__ B, u16* __restrict__ C,
    const int* __restrict__ gather, const int* __restrict__ offs,
    int Mstatic, int N, int K, int lda, long Bstride) {
  int e = blockIdx.z;
  int seg0 = 0, segM = Mstatic;
  if (offs) { seg0 = offs[e]; segM = offs[e + 1] - seg0; }
  int mt = blockIdx.y, nt = blockIdx.x;
  if (mt * 256 >= segM) return;
  const u16* Be = B + (long)e * Bstride;

  __shared__ __align__(16) u16 sm[65536];  // 128 KiB -> 1 block/CU

  int tid = threadIdx.x;
  int lane = tid & 63;
  int wv = tid >> 6, wm = wv >> 2, wn = wv & 3;
  int c4 = lane & 15, r4 = lane >> 4;

  // ---- staging addressing: thread covers (row = j*64 + tid>>3, chunk = tid&7) of a half-tile
  int srow = tid >> 3, schunk = tid & 7;
  int sswz8 = (schunk ^ (srow & 7)) * 8;   // pre-swizzled source col chunk
  int sOff = srow * 64 + schunk * 8;       // linear LDS dest (== wave base + lane*16B)

  u32 aoff[2][2], boff[2][2];              // element offsets, (h, j)
#pragma unroll
  for (int h = 0; h < 2; ++h)
#pragma unroll
    for (int j = 0; j < 2; ++j) {
      int rit = h * 128 + j * 64 + srow;
      int rl = mt * 256 + rit;
      if (rl >= segM) rl = mt * 256;       // clamp (masked at store)
      int ridx = seg0 + rl;
      u32 arow = gather ? (u32)gather[ridx] : (u32)ridx;
      aoff[h][j] = arow * (u32)lda + (u32)sswz8;
      boff[h][j] = (u32)(nt * 256 + rit) * (u32)K + (u32)sswz8;
    }

  // ---- ds_read lane addressing (row&7 == lane&7 for all frags)
  int swzv = (lane & 7) * 8;
  int aRL0 = c4 * 64 + ((r4 * 8) ^ swzv);  // kk=0
  int aRL1 = aRL0 ^ 32;                    // kk=1 (XOR bit5 in u16 units)
  int aB0 = wm * 8192, aB1 = 32768 + aB0;
  int bB0 = 16384 + (wn >> 1) * 8192 + (wn & 1) * 4096, bB1 = 32768 + bB0;

  f32x4 acc[8][4];
  bf16x8 a[8][2], b[4][2];
#pragma unroll
  for (int i = 0; i < 8; ++i)
#pragma unroll
    for (int j = 0; j < 4; ++j) acc[i][j] = f32x4{0.f, 0.f, 0.f, 0.f};

#define READ_A(PB, LO) do { _Pragma("unroll") \
  for (int mi = 0; mi < 4; ++mi) { \
    a[(LO) + mi][0] = *(const bf16x8*)&sm[(PB) + ((LO) + mi) * 1024 + aRL0]; \
    a[(LO) + mi][1] = *(const bf16x8*)&sm[(PB) + ((LO) + mi) * 1024 + aRL1]; \
  } } while (0)
#define READ_B(PB) do { _Pragma("unroll") \
  for (int ni = 0; ni < 4; ++ni) { \
    b[ni][0] = *(const bf16x8*)&sm[(PB) + ni * 1024 + aRL0]; \
    b[ni][1] = *(const bf16x8*)&sm[(PB) + ni * 1024 + aRL1]; \
  } } while (0)
#define MFMAQ(MI0, NI0) do { __builtin_amdgcn_s_setprio(1); \
  _Pragma("unroll") for (int mi = 0; mi < 4; ++mi) \
  _Pragma("unroll") for (int ni = 0; ni < 2; ++ni) \
  _Pragma("unroll") for (int kk = 0; kk < 2; ++kk) \
    acc[(MI0) + mi][(NI0) + ni] = __builtin_amdgcn_mfma_f32_16x16x32_bf16( \
        a[(MI0) + mi][kk], b[(NI0) + ni][kk], acc[(MI0) + mi][(NI0) + ni], 0, 0, 0); \
  __builtin_amdgcn_s_setprio(0); } while (0)
#define STAGE_A(PO, H, T) do { \
  gld_lds16(A + aoff[H][0] + (u32)((T) * 64), &sm[(PO) + (H) * 8192 + sOff]); \
  gld_lds16(A + aoff[H][1] + (u32)((T) * 64), &sm[(PO) + (H) * 8192 + 4096 + sOff]); \
} while (0)
#define STAGE_B(PO, H, T) do { \
  gld_lds16(Be + boff[H][0] + (u32)((T) * 64), &sm[(PO) + 16384 + (H) * 8192 + sOff]); \
  gld_lds16(Be + boff[H][1] + (u32)((T) * 64), &sm[(PO) + 16384 + (H) * 8192 + 4096 + sOff]); \
} while (0)

  // ---- prologue: tile0 (4 halves) + tile1 (3 halves); B(1)h1 is staged at iter0/ph1
  STAGE_A(0, 0, 0); STAGE_A(0, 1, 0); STAGE_B(0, 0, 0); STAGE_B(0, 1, 0);
  STAGE_B(32768, 0, 1); STAGE_A(32768, 0, 1); STAGE_A(32768, 1, 1);
  VMC6;   // drains to 6 outstanding -> tile0's 8 loads have landed
  bar();

  int niter = K >> 7;  // (K/64)/2 K-tiles per iteration
  for (int it = 0; it < niter; ++it) {
    int t2 = 2 * it + 2, t3 = 2 * it + 3;
    bool nl = (it + 1 < niter);
    // ph1: read tile-even A-lo + B(all); stage B(odd)h1
    READ_A(aB0, 0); READ_B(bB0);
    STAGE_B(32768, 1, 2 * it + 1);
    bar(); LGKM0; MFMAQ(0, 0); bar();
    // ph2: read A-hi; stage B(t2)h0 (B-even region free since ph1)
    READ_A(aB0, 4);
    if (nl) STAGE_B(0, 0, t2);
    bar(); LGKM0; MFMAQ(0, 2); bar();
    // ph3: stage A(t2)h0 (A-even region free since ph2)
    if (nl) STAGE_A(0, 0, t2);
    bar(); MFMAQ(4, 0); bar();
    // ph4: stage A(t2)h1; counted vmcnt -> tile-odd fully landed
    if (nl) { STAGE_A(0, 1, t2); VMC6; } else { VMC0; }
    bar(); MFMAQ(4, 2); bar();
    // ph5: read tile-odd A-lo + B(all); stage B(t2)h1
    READ_A(aB1, 0); READ_B(bB1);
    if (nl) STAGE_B(0, 1, t2);
    bar(); LGKM0; MFMAQ(0, 0); bar();
    // ph6: read A-hi; stage B(t3)h0
    READ_A(aB1, 4);
    if (nl) STAGE_B(32768, 0, t3);
    bar(); LGKM0; MFMAQ(0, 2); bar();
    // ph7: stage A(t3)h0
    if (nl) STAGE_A(32768, 0, t3);
    bar(); MFMAQ(4, 0); bar();
    // ph8: stage A(t3)h1; counted vmcnt -> t2 fully landed for next ph1
    if (nl) { STAGE_A(32768, 1, t3); VMC6; }
    bar(); MFMAQ(4, 2); bar();
  }

#undef READ_A
#undef READ_B
#undef MFMAQ
#undef STAGE_A
#undef STAGE_B

  // ---- epilogue: C/D layout col=lane&15, row=(lane>>4)*4+reg (m89-verified)
#pragma unroll
  for (int mi = 0; mi < 8; ++mi) {
#pragma unroll
    for (int r = 0; r < 4; ++r) {
      int lr = wm * 128 + mi * 16 + r4 * 4 + r;
      if (mt * 256 + lr < segM) {
        long base = (long)(seg0 + mt * 256 + lr) * N + nt * 256 + wn * 64 + c4;
#pragma unroll
        for (int ni = 0; ni < 4; ++ni) C[base + ni * 16] = f2bf(acc[mi][ni][r]);
      }
    }
  }
}

extern "C" void kernel_launch(void* const* d_in, const int* in_sizes, int n_in,
                              void* d_out, int out_size, void* d_ws, size_t ws_size,
                              hipStream_t stream) {
  const float* hidden = (const float*)d_in[0];       // [4096, 2048]
  const float* gate_weight = (const float*)d_in[1];  // [16, 2048]
  const float* bias = (const float*)d_in[2];         // [16]
  const float* gate_w = (const float*)d_in[3];       // [16, 1024, 2048]
  const float* up_w = (const float*)d_in[4];         // [16, 1024, 2048]
  const float* down_w = (const float*)d_in[5];       // [16, 2048, 1024]
  const float* shg = (const float*)d_in[6];          // [2048, 2048]
  const float* shu = (const float*)d_in[7];          // [2048, 2048]
  const float* shd = (const float*)d_in[8];          // [2048, 2048]
  float* out = (float*)d_out;                        // [4096, 2048]

  char* p = (char*)d_ws;
  auto alloc = [&](size_t bytes) {
    char* q = p;
    p += (bytes + 255) & ~(size_t)255;
    return q;
  };
  u16* Xb = (u16*)alloc((size_t)NTOK * HDIM * 2);                 // 16 MB bf16 hidden
  u16* GUb = (u16*)alloc((size_t)NEXP * 2 * FMOE * HDIM * 2);     // 128 MB [e][gate;up]
  u16* Db = (u16*)alloc((size_t)NEXP * HDIM * FMOE * 2);          // 64 MB
  u16* SGUb = (u16*)alloc((size_t)2 * FSH * HDIM * 2);            // 16 MB [gate;up]
  u16* SDb = (u16*)alloc((size_t)HDIM * FSH * 2);                 // 8 MB
  u16* gu_out = (u16*)alloc((size_t)NTOK * 4 * 2 * FMOE * 2);     // 64 MB routed gate|up
  int* topki = (int*)alloc((size_t)NTOK * 4 * 4);
  float* topkw = (float*)alloc((size_t)NTOK * 4 * 4);
  int* counts = (int*)alloc(64);
  int* offs = (int*)alloc(128);
  int* ltok = (int*)alloc((size_t)NTOK * 4 * 4);
  int* slotmap = (int*)alloc((size_t)NTOK * 4 * 4);
  // aliases into GUb, valid AFTER the routed gate/up GEMM consumed the weights:
  u16* Y = GUb;                                                   // 64 MB routed down out
  u16* gs_out = GUb + (size_t)NTOK * 4 * HDIM;                    // 32 MB shared gate|up
  u16* SY = gs_out + (size_t)NTOK * 2 * FSH;                      // 16 MB shared down out

  // fp32 -> bf16 conversions
  cvt_bf16<<<8192, 256, 0, stream>>>(hidden, Xb, (long)NTOK * HDIM / 4);
  cvt_pair_moe<<<dim3(2048, 1, NEXP), 256, 0, stream>>>(gate_w, up_w, GUb);
  cvt_bf16<<<32768, 256, 0, stream>>>(down_w, Db, (long)NEXP * HDIM * FMOE / 4);
  cvt_bf16<<<4096, 256, 0, stream>>>(shg, SGUb, (long)FSH * HDIM / 4);
  cvt_bf16<<<4096, 256, 0, stream>>>(shu, SGUb + (size_t)FSH * HDIM, (long)FSH * HDIM / 4);
  cvt_bf16<<<4096, 256, 0, stream>>>(shd, SDb, (long)HDIM * FSH / 4);

  // routing + expert lists
  hipMemsetAsync(counts, 0, 64, stream);
  routing_kernel<<<NTOK / 4, 256, 0, stream>>>(hidden, gate_weight, bias, topki, topkw, counts);
  prefix16<<<1, 64, 0, stream>>>(counts, offs);
  fill_lists<<<NEXP, 256, 0, stream>>>(topki, offs, ltok, slotmap);

  // routed fused gate+up GEMM: [rows x 2048] = X(gathered) @ GU[e]^T, then in-place silu
  gemm256<<<dim3(2 * FMOE / 256, NTOK / 256, NEXP), 512, 0, stream>>>(
      Xb, GUb, gu_out, ltok, offs, 0, 2 * FMOE, HDIM, HDIM, (long)2 * FMOE * HDIM);
  silu_mul_pair<FMOE><<<16384, 256, 0, stream>>>(gu_out, offs + NEXP, 0);
  // routed down: [rows x 2048] = act @ D[e]^T, bf16 store in list order
  gemm256<<<dim3(HDIM / 256, NTOK / 256, NEXP), 512, 0, stream>>>(
      gu_out, Db, Y, nullptr, offs, 0, HDIM, FMOE, 2 * FMOE, (long)HDIM * FMOE);

  // shared expert: fused gate+up, silu, down
  gemm256<<<dim3(2 * FSH / 256, NTOK / 256, 1), 512, 0, stream>>>(
      Xb, SGUb, gs_out, nullptr, nullptr, NTOK, 2 * FSH, HDIM, HDIM, 0);
  silu_mul_pair<FSH><<<8192, 256, 0, stream>>>(gs_out, nullptr, NTOK);
  gemm256<<<dim3(HDIM / 256, NTOK / 256, 1), 512, 0, stream>>>(
      gs_out, SDb, SY, nullptr, nullptr, NTOK, HDIM, FSH, 2 * FSH, 0);

  // final: out[t] = SY[t] + sum_k w * Y[slot]
  reduce_out<<<8192, 256, 0, stream>>>(SY, Y, slotmap, topkw, out);
}

// Round 2
// 1102.103 us; speedup vs baseline: 1.3863x; 1.3863x over previous
//
#include <hip/hip_runtime.h>
#include <cstdint>

typedef unsigned int u32;
typedef unsigned short u16;
typedef __bf16 bf16x8 __attribute__((ext_vector_type(8)));
typedef float f32x4 __attribute__((ext_vector_type(4)));

#define NTOK 4096
#define HDIM 2048
#define FMOE 1024
#define FSH  2048
#define NEXP 16

__device__ __forceinline__ u16 f2bf(float f) {
  u32 u = __float_as_uint(f);
  u32 r = (u + 0x7fffu + ((u >> 16) & 1u)) >> 16;
  return (u16)r;
}
__device__ __forceinline__ float bf2f(u16 h) {
  return __uint_as_float(((u32)h) << 16);
}

__device__ __forceinline__ void gld_lds16(const void* g, void* l) {
  __builtin_amdgcn_global_load_lds(
      (const __attribute__((address_space(1))) u32*)g,
      (__attribute__((address_space(3))) u32*)l, 16, 0, 0);
}

// ---------------- fp32 -> bf16 conversion (vectorized x4) ----------------
__global__ void cvt_bf16(const float* __restrict__ in, u16* __restrict__ out, long n4) {
  long i = (long)blockIdx.x * blockDim.x + threadIdx.x;
  if (i < n4) {
    float4 v = ((const float4*)in)[i];
    ushort4 o;
    o.x = f2bf(v.x); o.y = f2bf(v.y); o.z = f2bf(v.z); o.w = f2bf(v.w);
    ((ushort4*)out)[i] = o;
  }
}

// convert gate_w + up_w into concatenated per-expert layout GU[e][0:F]=gate, GU[e][F:2F]=up
__global__ void cvt_pair_moe(const float* __restrict__ g, const float* __restrict__ u,
                             u16* __restrict__ dst) {
  int e = blockIdx.z;
  const long n4 = (long)FMOE * HDIM / 4;
  long i = (long)blockIdx.x * blockDim.x + threadIdx.x;
  const float4* gs = (const float4*)(g + (long)e * FMOE * HDIM);
  const float4* us = (const float4*)(u + (long)e * FMOE * HDIM);
  ushort4* d = (ushort4*)(dst + (long)e * 2 * FMOE * HDIM);
  float4 v = gs[i];
  ushort4 o;
  o.x = f2bf(v.x); o.y = f2bf(v.y); o.z = f2bf(v.z); o.w = f2bf(v.w);
  d[i] = o;
  v = us[i];
  o.x = f2bf(v.x); o.y = f2bf(v.y); o.z = f2bf(v.z); o.w = f2bf(v.w);
  d[n4 + i] = o;
}

// ---------------- routing: gate weights staged in LDS, one wave per token ----------------
__global__ __launch_bounds__(256) void routing_kernel(
    const float* __restrict__ hidden, const float* __restrict__ gw,
    const float* __restrict__ bias, int* __restrict__ topk_idx,
    float* __restrict__ topk_w, int* __restrict__ counts) {
  __shared__ float gws[8 * HDIM];  // 64 KB: 8 experts per pass
  int tid = threadIdx.x, lane = tid & 63, wv = tid >> 6;
  int t = blockIdx.x * 4 + wv;
  float acc[NEXP];
#pragma unroll
  for (int n = 0; n < NEXP; ++n) acc[n] = 0.f;
  const float4* h4 = (const float4*)(hidden + (long)t * HDIM);

  for (int half = 0; half < 2; ++half) {
    for (int i = tid; i < 8 * HDIM / 4; i += 256)
      ((float4*)gws)[i] = ((const float4*)(gw + half * 8 * HDIM))[i];
    __syncthreads();
#pragma unroll
    for (int j0 = 0; j0 < HDIM / 4; j0 += 64) {
      int j = j0 + lane;
      float4 hv = h4[j];
#pragma unroll
      for (int e = 0; e < 8; ++e) {
        float4 g = ((const float4*)gws)[e * (HDIM / 4) + j];
        acc[half * 8 + e] += hv.x * g.x + hv.y * g.y + hv.z * g.z + hv.w * g.w;
      }
    }
    __syncthreads();
  }
#pragma unroll
  for (int n = 0; n < NEXP; ++n) {
    float v = acc[n];
    for (int m = 32; m; m >>= 1) v += __shfl_xor(v, m);
    acc[n] = v;
  }
  if (lane == 0) {
    float sc[NEXP], scb[NEXP];
#pragma unroll
    for (int n = 0; n < NEXP; ++n) {
      sc[n] = 1.f / (1.f + expf(-acc[n]));
      scb[n] = sc[n] + bias[n];
    }
    float gs[4];
#pragma unroll
    for (int g = 0; g < 4; ++g) {
      float m1 = -1e30f, m2 = -1e30f;
#pragma unroll
      for (int j = 0; j < 4; ++j) {
        float v = scb[4 * g + j];
        if (v > m1) { m2 = m1; m1 = v; } else if (v > m2) { m2 = v; }
      }
      gs[g] = m1 + m2;
    }
    int g1 = -1, g2 = -1;
    { float b = -1e30f; for (int g = 0; g < 4; ++g) if (gs[g] > b) { b = gs[g]; g1 = g; } }
    { float b = -1e30f; for (int g = 0; g < 4; ++g) if (g != g1 && gs[g] > b) { b = gs[g]; g2 = g; } }
    bool used[NEXP];
#pragma unroll
    for (int n = 0; n < NEXP; ++n) used[n] = false;
    int sel[4]; float wts[4]; float s = 0.f;
    for (int k = 0; k < 4; ++k) {
      float b = -1e30f; int bi = 0;
      for (int n = 0; n < NEXP; ++n) {
        int g = n >> 2;
        if ((g == g1 || g == g2) && !used[n] && scb[n] > b) { b = scb[n]; bi = n; }
      }
      used[bi] = true; sel[k] = bi; wts[k] = sc[bi]; s += sc[bi];
    }
    float inv = 2.5f / (s + 1e-20f);
    for (int k = 0; k < 4; ++k) {
      topk_idx[t * 4 + k] = sel[k];
      topk_w[t * 4 + k] = wts[k] * inv;
      atomicAdd(&counts[sel[k]], 1);
    }
  }
}

// ---------------- prefix over 16 counts ----------------
__global__ void prefix16(const int* __restrict__ counts, int* __restrict__ offs) {
  if (threadIdx.x == 0) {
    int s = 0;
    for (int e = 0; e < NEXP; ++e) { offs[e] = s; s += counts[e]; }
    offs[NEXP] = s;
  }
}

// ---------------- deterministic ordered compaction + slot map ----------------
__global__ void fill_lists(const int* __restrict__ topk_idx,
                           const int* __restrict__ offs, int* __restrict__ ltok,
                           int* __restrict__ slotmap) {
  int e = blockIdx.x;
  int tid = threadIdx.x, lane = tid & 63, wv = tid >> 6;
  __shared__ int cursor;
  __shared__ int wcnt[4];
  if (tid == 0) cursor = offs[e];
  __syncthreads();
  for (int base = 0; base < NTOK; base += 256) {
    int t = base + tid;
    int flag = 0, kk = 0;
#pragma unroll
    for (int k = 0; k < 4; ++k) {
      if (topk_idx[t * 4 + k] == e) { flag = 1; kk = k; }
    }
    unsigned long long b = __ballot(flag);
    if (lane == 0) wcnt[wv] = __popcll(b);
    __syncthreads();
    int pre = 0;
    for (int i = 0; i < wv; ++i) pre += wcnt[i];
    int pos = cursor + pre + __popcll(b & ((1ull << lane) - 1ull));
    if (flag) { ltok[pos] = t; slotmap[t * 4 + kk] = pos; }
    __syncthreads();
    if (tid == 0) cursor += wcnt[0] + wcnt[1] + wcnt[2] + wcnt[3];
    __syncthreads();
  }
}

// ---------------- in-place paired silu ----------------
template <int F>
__global__ void silu_mul_pair(u16* __restrict__ gu, const int* __restrict__ nrows_ptr,
                              int nrows_static) {
  int rows = nrows_ptr ? *nrows_ptr : nrows_static;
  long total4 = (long)rows * (F / 4);
  long i = (long)blockIdx.x * blockDim.x + threadIdx.x;
  if (i < total4) {
    long row = i / (F / 4);
    int f4 = (int)(i - row * (F / 4));
    ushort4* rowp = (ushort4*)(gu + row * 2 * F);
    ushort4 gv = rowp[f4];
    ushort4 uv = rowp[F / 4 + f4];
    float gf, uf, sv;
    ushort4 o;
    gf = bf2f(gv.x); uf = bf2f(uv.x); sv = gf / (1.f + __expf(-gf)); o.x = f2bf(sv * uf);
    gf = bf2f(gv.y); uf = bf2f(uv.y); sv = gf / (1.f + __expf(-gf)); o.y = f2bf(sv * uf);
    gf = bf2f(gv.z); uf = bf2f(uv.z); sv = gf / (1.f + __expf(-gf)); o.z = f2bf(sv * uf);
    gf = bf2f(gv.w); uf = bf2f(uv.w); sv = gf / (1.f + __expf(-gf)); o.w = f2bf(sv * uf);
    rowp[f4] = o;
  }
}

// ---------------- final reduce ----------------
__global__ void reduce_out(const u16* __restrict__ SY, const u16* __restrict__ Y,
                           const int* __restrict__ slotmap, const float* __restrict__ tkw,
                           float* __restrict__ out) {
  long i = (long)blockIdx.x * blockDim.x + threadIdx.x;  // over NTOK*HDIM/4
  int t = (int)(i >> 9);       // HDIM/4 = 512
  int c4 = (int)(i & 511);
  ushort4 s = ((const ushort4*)SY)[i];
  float4 o;
  o.x = bf2f(s.x); o.y = bf2f(s.y); o.z = bf2f(s.z); o.w = bf2f(s.w);
#pragma unroll
  for (int k = 0; k < 4; ++k) {
    int sl = slotmap[t * 4 + k];
    float w = tkw[t * 4 + k];
    ushort4 y = ((const ushort4*)Y)[(long)sl * 512 + c4];
    o.x += w * bf2f(y.x);
    o.y += w * bf2f(y.y);
    o.z += w * bf2f(y.z);
    o.w += w * bf2f(y.w);
  }
  ((float4*)out)[i] = o;
}

// ================= 256x256 bf16 GEMM-BT, 8-phase counted-vmcnt schedule (v2) =================
// 512 thr = 8 waves (2M x 4N); per-wave 128x64 out; BK=64; 128 KiB LDS, 2 buffers.
// v2: phase->fragment mapping restructured to cut fragment live set 96 -> 64 VGPR (round-1
// version spilled: WRITE_SIZE +27MB scratch). Per K-tile quadrant order Q(0,lo) Q(0,hi)
// Q(4,hi) Q(4,lo); reads per phase: 12 / 4 / 8 / 0 ds_read_b128.
// LDS (u16 idx): buf p at p*32768; A rows linear at row*64; B at 16384 + row*64.
// Swizzle: col-chunk ^= (row&7) on global SOURCE + on ds_read addr (write side linear).
#define LGKM0 asm volatile("s_waitcnt lgkmcnt(0)" ::: "memory")
#define VMC4  asm volatile("s_waitcnt vmcnt(4)" ::: "memory")
#define VMC0  asm volatile("s_waitcnt vmcnt(0)" ::: "memory")
__device__ __forceinline__ void bar() {
  asm volatile("" ::: "memory");
  __builtin_amdgcn_s_barrier();
  asm volatile("" ::: "memory");
}

__global__ __launch_bounds__(512, 2) void gemm256(
    const u16* __restrict__ A, const u16* __restrict__ B, u16* __restrict__ C,
    const int* __restrict__ gather, const int* __restrict__ offs,
    int Mstatic, int N, int K, int lda, long Bstride) {
  int e = blockIdx.z;
  int seg0 = 0, segM = Mstatic;
  if (offs) { seg0 = offs[e]; segM = offs[e + 1] - seg0; }
  int mt = blockIdx.y, nt = blockIdx.x;
  if (mt * 256 >= segM) return;
  const u16* Be = B + (long)e * Bstride;

  __shared__ __align__(16) u16 sm[65536];  // 128 KiB -> 1 block/CU

  int tid = threadIdx.x;
  int lane = tid & 63;
  int wv = tid >> 6, wm = wv >> 2, wn = wv & 3;
  int c4 = lane & 15, r4 = lane >> 4;

  // ---- staging addressing: thread covers (row = j*64 + tid>>3, chunk = tid&7) of a half-tile
  int srow = tid >> 3, schunk = tid & 7;
  int sswz8 = (schunk ^ (srow & 7)) * 8;   // pre-swizzled source col chunk
  int sOff = srow * 64 + schunk * 8;       // linear LDS dest

  u32 aoff[2][2], boff[2][2];              // element offsets, (h, j)
#pragma unroll
  for (int h = 0; h < 2; ++h)
#pragma unroll
    for (int j = 0; j < 2; ++j) {
      int rit = h * 128 + j * 64 + srow;
      int rl = mt * 256 + rit;
      if (rl >= segM) rl = mt * 256;       // clamp (masked at store)
      int ridx = seg0 + rl;
      u32 arow = gather ? (u32)gather[ridx] : (u32)ridx;
      aoff[h][j] = arow * (u32)lda + (u32)sswz8;
      boff[h][j] = (u32)(nt * 256 + rit) * (u32)K + (u32)sswz8;
    }

  // ---- ds_read lane addressing (row&7 == lane&7 for all frags)
  int swzv = (lane & 7) * 8;
  int aRL0 = c4 * 64 + ((r4 * 8) ^ swzv);  // kk=0
  int aRL1 = aRL0 ^ 32;                    // kk=1
  int aB0 = wm * 8192, aB1 = 32768 + aB0;
  int bB0 = 16384 + wn * 4096, bB1 = 32768 + bB0;

  f32x4 acc[8][4];
  bf16x8 af[4][2], bLo[2][2], bHi[2][2];
#pragma unroll
  for (int i = 0; i < 8; ++i)
#pragma unroll
    for (int j = 0; j < 4; ++j) acc[i][j] = f32x4{0.f, 0.f, 0.f, 0.f};

#define READ_A8(BASE) do { _Pragma("unroll") \
  for (int mi = 0; mi < 4; ++mi) { \
    af[mi][0] = *(const bf16x8*)&sm[(BASE) + mi * 1024 + aRL0]; \
    af[mi][1] = *(const bf16x8*)&sm[(BASE) + mi * 1024 + aRL1]; \
  } } while (0)
#define READ_B4(BASE, BARR) do { _Pragma("unroll") \
  for (int ni = 0; ni < 2; ++ni) { \
    BARR[ni][0] = *(const bf16x8*)&sm[(BASE) + ni * 1024 + aRL0]; \
    BARR[ni][1] = *(const bf16x8*)&sm[(BASE) + ni * 1024 + aRL1]; \
  } } while (0)
#define MFMAQ(MI0, NI0, BARR) do { __builtin_amdgcn_s_setprio(1); \
  _Pragma("unroll") for (int mi = 0; mi < 4; ++mi) \
  _Pragma("unroll") for (int ni = 0; ni < 2; ++ni) \
  _Pragma("unroll") for (int kk = 0; kk < 2; ++kk) \
    acc[(MI0) + mi][(NI0) + ni] = __builtin_amdgcn_mfma_f32_16x16x32_bf16( \
        af[mi][kk], BARR[ni][kk], acc[(MI0) + mi][(NI0) + ni], 0, 0, 0); \
  __builtin_amdgcn_s_setprio(0); } while (0)
#define STAGE_A(PO, H, T) do { \
  gld_lds16(A + aoff[H][0] + (u32)((T) * 64), &sm[(PO) + (H) * 8192 + sOff]); \
  gld_lds16(A + aoff[H][1] + (u32)((T) * 64), &sm[(PO) + (H) * 8192 + 4096 + sOff]); \
} while (0)
#define STAGE_B(PO, H, T) do { \
  gld_lds16(Be + boff[H][0] + (u32)((T) * 64), &sm[(PO) + 16384 + (H) * 8192 + sOff]); \
  gld_lds16(Be + boff[H][1] + (u32)((T) * 64), &sm[(PO) + 16384 + (H) * 8192 + 4096 + sOff]); \
} while (0)

  // ---- prologue: tile0 (4 halves) + B of tile1 (2 halves); A of tile1 staged at ph1/ph2
  STAGE_A(0, 0, 0); STAGE_A(0, 1, 0); STAGE_B(0, 0, 0); STAGE_B(0, 1, 0);
  STAGE_B(32768, 0, 1); STAGE_B(32768, 1, 1);
  VMC4;   // tile0's 8 loads landed; Bod(1) outstanding
  bar();

  int niter = K >> 7;  // 2 K-tiles per iteration
  for (int it = 0; it < niter; ++it) {
    int to = 2 * it + 1, t2 = 2 * it + 2, t3 = 2 * it + 3;
    bool nl = (it + 1 < niter);
    // ph1: read a0-3(E) + bLo(E) (12 reads); stage Aod h0 (tile 2it+1)
    READ_A8(aB0); READ_B4(bB0, bLo);
    STAGE_A(32768, 0, to);
    bar(); LGKM0; MFMAQ(0, 0, bLo); bar();
    // ph2: read bHi(E) (4); stage Aod h1
    READ_B4(bB0 + 2048, bHi);
    STAGE_A(32768, 1, to);
    bar(); LGKM0; MFMAQ(0, 2, bHi); bar();
    // ph3: read a4-7(E) (8); stage Bev h0 (t2)  [Bev free after ph2]
    READ_A8(aB0 + 4096);
    if (nl) STAGE_B(0, 0, t2);
    bar(); LGKM0; MFMAQ(4, 2, bHi); bar();
    // ph4: no reads; stage Bev h1 (t2); counted vmcnt -> odd tile (2it+1) landed
    if (nl) { STAGE_B(0, 1, t2); VMC4; } else { VMC0; }
    bar(); MFMAQ(4, 0, bLo); bar();
    // ph5: read a0-3(O) + bLo(O); stage Aev h0 (t2)  [Aev free after ph3]
    READ_A8(aB1); READ_B4(bB1, bLo);
    if (nl) STAGE_A(0, 0, t2);
    bar(); LGKM0; MFMAQ(0, 0, bLo); bar();
    // ph6: read bHi(O); stage Aev h1 (t2)
    READ_B4(bB1 + 2048, bHi);
    if (nl) STAGE_A(0, 1, t2);
    bar(); LGKM0; MFMAQ(0, 2, bHi); bar();
    // ph7: read a4-7(O); stage Bod h0 (t3)  [Bod free after ph6]
    READ_A8(aB1 + 4096);
    if (nl) STAGE_B(32768, 0, t3);
    bar(); LGKM0; MFMAQ(4, 2, bHi); bar();
    // ph8: stage Bod h1 (t3); counted vmcnt -> even tile (t2) landed for next ph1
    if (nl) { STAGE_B(32768, 1, t3); VMC4; }
    bar(); MFMAQ(4, 0, bLo); bar();
  }

#undef READ_A8
#undef READ_B4
#undef MFMAQ
#undef STAGE_A
#undef STAGE_B

  // ---- epilogue: C/D layout col=lane&15, row=(lane>>4)*4+reg (m89-verified)
#pragma unroll
  for (int mi = 0; mi < 8; ++mi) {
#pragma unroll
    for (int r = 0; r < 4; ++r) {
      int lr = wm * 128 + mi * 16 + r4 * 4 + r;
      if (mt * 256 + lr < segM) {
        long base = (long)(seg0 + mt * 256 + lr) * N + nt * 256 + wn * 64 + c4;
#pragma unroll
        for (int ni = 0; ni < 4; ++ni) C[base + ni * 16] = f2bf(acc[mi][ni][r]);
      }
    }
  }
}

extern "C" void kernel_launch(void* const* d_in, const int* in_sizes, int n_in,
                              void* d_out, int out_size, void* d_ws, size_t ws_size,
                              hipStream_t stream) {
  const float* hidden = (const float*)d_in[0];       // [4096, 2048]
  const float* gate_weight = (const float*)d_in[1];  // [16, 2048]
  const float* bias = (const float*)d_in[2];         // [16]
  const float* gate_w = (const float*)d_in[3];       // [16, 1024, 2048]
  const float* up_w = (const float*)d_in[4];         // [16, 1024, 2048]
  const float* down_w = (const float*)d_in[5];       // [16, 2048, 1024]
  const float* shg = (const float*)d_in[6];          // [2048, 2048]
  const float* shu = (const float*)d_in[7];          // [2048, 2048]
  const float* shd = (const float*)d_in[8];          // [2048, 2048]
  float* out = (float*)d_out;                        // [4096, 2048]

  char* p = (char*)d_ws;
  auto alloc = [&](size_t bytes) {
    char* q = p;
    p += (bytes + 255) & ~(size_t)255;
    return q;
  };
  u16* Xb = (u16*)alloc((size_t)NTOK * HDIM * 2);                 // 16 MB bf16 hidden
  u16* GUb = (u16*)alloc((size_t)NEXP * 2 * FMOE * HDIM * 2);     // 128 MB [e][gate;up]
  u16* Db = (u16*)alloc((size_t)NEXP * HDIM * FMOE * 2);          // 64 MB
  u16* SGUb = (u16*)alloc((size_t)2 * FSH * HDIM * 2);            // 16 MB [gate;up]
  u16* SDb = (u16*)alloc((size_t)HDIM * FSH * 2);                 // 8 MB
  u16* gu_out = (u16*)alloc((size_t)NTOK * 4 * 2 * FMOE * 2);     // 64 MB routed gate|up
  int* topki = (int*)alloc((size_t)NTOK * 4 * 4);
  float* topkw = (float*)alloc((size_t)NTOK * 4 * 4);
  int* counts = (int*)alloc(64);
  int* offs = (int*)alloc(128);
  int* ltok = (int*)alloc((size_t)NTOK * 4 * 4);
  int* slotmap = (int*)alloc((size_t)NTOK * 4 * 4);
  // aliases into GUb, valid AFTER the routed gate/up GEMM consumed the weights:
  u16* Y = GUb;                                                   // 64 MB routed down out
  u16* gs_out = GUb + (size_t)NTOK * 4 * HDIM;                    // 32 MB shared gate|up
  u16* SY = gs_out + (size_t)NTOK * 2 * FSH;                      // 16 MB shared down out

  // fp32 -> bf16 conversions
  cvt_bf16<<<8192, 256, 0, stream>>>(hidden, Xb, (long)NTOK * HDIM / 4);
  cvt_pair_moe<<<dim3(2048, 1, NEXP), 256, 0, stream>>>(gate_w, up_w, GUb);
  cvt_bf16<<<32768, 256, 0, stream>>>(down_w, Db, (long)NEXP * HDIM * FMOE / 4);
  cvt_bf16<<<4096, 256, 0, stream>>>(shg, SGUb, (long)FSH * HDIM / 4);
  cvt_bf16<<<4096, 256, 0, stream>>>(shu, SGUb + (size_t)FSH * HDIM, (long)FSH * HDIM / 4);
  cvt_bf16<<<4096, 256, 0, stream>>>(shd, SDb, (long)HDIM * FSH / 4);

  // routing + expert lists
  hipMemsetAsync(counts, 0, 64, stream);
  routing_kernel<<<NTOK / 4, 256, 0, stream>>>(hidden, gate_weight, bias, topki, topkw, counts);
  prefix16<<<1, 64, 0, stream>>>(counts, offs);
  fill_lists<<<NEXP, 256, 0, stream>>>(topki, offs, ltok, slotmap);

  // routed fused gate+up GEMM: [rows x 2048] = X(gathered) @ GU[e]^T, then in-place silu
  gemm256<<<dim3(2 * FMOE / 256, NTOK / 256, NEXP), 512, 0, stream>>>(
      Xb, GUb, gu_out, ltok, offs, 0, 2 * FMOE, HDIM, HDIM, (long)2 * FMOE * HDIM);
  silu_mul_pair<FMOE><<<16384, 256, 0, stream>>>(gu_out, offs + NEXP, 0);
  // routed down: [rows x 2048] = act @ D[e]^T, bf16 store in list order
  gemm256<<<dim3(HDIM / 256, NTOK / 256, NEXP), 512, 0, stream>>>(
      gu_out, Db, Y, nullptr, offs, 0, HDIM, FMOE, 2 * FMOE, (long)HDIM * FMOE);

  // shared expert: fused gate+up, silu, down
  gemm256<<<dim3(2 * FSH / 256, NTOK / 256, 1), 512, 0, stream>>>(
      Xb, SGUb, gs_out, nullptr, nullptr, NTOK, 2 * FSH, HDIM, HDIM, 0);
  silu_mul_pair<FSH><<<8192, 256, 0, stream>>>(gs_out, nullptr, NTOK);
  gemm256<<<dim3(HDIM / 256, NTOK / 256, 1), 512, 0, stream>>>(
      gs_out, SDb, SY, nullptr, nullptr, NTOK, HDIM, FSH, 2 * FSH, 0);

  // final: out[t] = SY[t] + sum_k w * Y[slot]
  reduce_out<<<8192, 256, 0, stream>>>(SY, Y, slotmap, topkw, out);
}

// Round 4
// 962.782 us; speedup vs baseline: 1.5870x; 1.1447x over previous
//
#include <hip/hip_runtime.h>
#include <cstdint>

typedef unsigned int u32;
typedef unsigned short u16;
typedef __bf16 bf16x8 __attribute__((ext_vector_type(8)));
typedef float f32x4 __attribute__((ext_vector_type(4)));

#define NTOK 4096
#define HDIM 2048
#define FMOE 1024
#define FSH  2048
#define NEXP 16

__device__ __forceinline__ u16 f2bf(float f) {
  u32 u = __float_as_uint(f);
  u32 r = (u + 0x7fffu + ((u >> 16) & 1u)) >> 16;
  return (u16)r;
}
__device__ __forceinline__ float bf2f(u16 h) {
  return __uint_as_float(((u32)h) << 16);
}

__device__ __forceinline__ void gld_lds16(const void* g, void* l) {
  __builtin_amdgcn_global_load_lds(
      (const __attribute__((address_space(1))) u32*)g,
      (__attribute__((address_space(3))) u32*)l, 16, 0, 0);
}

// ---------------- fp32 -> bf16 conversion (vectorized x4) ----------------
__global__ void cvt_bf16(const float* __restrict__ in, u16* __restrict__ out, long n4) {
  long i = (long)blockIdx.x * blockDim.x + threadIdx.x;
  if (i < n4) {
    float4 v = ((const float4*)in)[i];
    ushort4 o;
    o.x = f2bf(v.x); o.y = f2bf(v.y); o.z = f2bf(v.z); o.w = f2bf(v.w);
    ((ushort4*)out)[i] = o;
  }
}

// convert gate_w + up_w into concatenated per-expert layout GU[e][0:F]=gate, GU[e][F:2F]=up
__global__ void cvt_pair_moe(const float* __restrict__ g, const float* __restrict__ u,
                             u16* __restrict__ dst) {
  int e = blockIdx.z;
  const long n4 = (long)FMOE * HDIM / 4;
  long i = (long)blockIdx.x * blockDim.x + threadIdx.x;
  const float4* gs = (const float4*)(g + (long)e * FMOE * HDIM);
  const float4* us = (const float4*)(u + (long)e * FMOE * HDIM);
  ushort4* d = (ushort4*)(dst + (long)e * 2 * FMOE * HDIM);
  float4 v = gs[i];
  ushort4 o;
  o.x = f2bf(v.x); o.y = f2bf(v.y); o.z = f2bf(v.z); o.w = f2bf(v.w);
  d[i] = o;
  v = us[i];
  o.x = f2bf(v.x); o.y = f2bf(v.y); o.z = f2bf(v.z); o.w = f2bf(v.w);
  d[n4 + i] = o;
}

// ---------------- routing: gate weights staged in LDS, one wave per token ----------------
// v3: NO atomics (round-2 counters: 16384 same-cacheline atomicAdds serialized ~13ns each
// = 216us with all pipes idle). Counting moved to count_prefix below.
__global__ __launch_bounds__(256) void routing_kernel(
    const float* __restrict__ hidden, const float* __restrict__ gw,
    const float* __restrict__ bias, int* __restrict__ topk_idx,
    float* __restrict__ topk_w) {
  __shared__ float gws[8 * HDIM];  // 64 KB: 8 experts per pass
  int tid = threadIdx.x, lane = tid & 63, wv = tid >> 6;
  int t = blockIdx.x * 4 + wv;
  float acc[NEXP];
#pragma unroll
  for (int n = 0; n < NEXP; ++n) acc[n] = 0.f;
  const float4* h4 = (const float4*)(hidden + (long)t * HDIM);

  for (int half = 0; half < 2; ++half) {
    for (int i = tid; i < 8 * HDIM / 4; i += 256)
      ((float4*)gws)[i] = ((const float4*)(gw + half * 8 * HDIM))[i];
    __syncthreads();
#pragma unroll
    for (int j0 = 0; j0 < HDIM / 4; j0 += 64) {
      int j = j0 + lane;
      float4 hv = h4[j];
#pragma unroll
      for (int e = 0; e < 8; ++e) {
        float4 g = ((const float4*)gws)[e * (HDIM / 4) + j];
        acc[half * 8 + e] += hv.x * g.x + hv.y * g.y + hv.z * g.z + hv.w * g.w;
      }
    }
    __syncthreads();
  }
#pragma unroll
  for (int n = 0; n < NEXP; ++n) {
    float v = acc[n];
    for (int m = 32; m; m >>= 1) v += __shfl_xor(v, m);
    acc[n] = v;
  }
  if (lane == 0) {
    float sc[NEXP], scb[NEXP];
#pragma unroll
    for (int n = 0; n < NEXP; ++n) {
      sc[n] = 1.f / (1.f + expf(-acc[n]));
      scb[n] = sc[n] + bias[n];
    }
    float gs[4];
#pragma unroll
    for (int g = 0; g < 4; ++g) {
      float m1 = -1e30f, m2 = -1e30f;
#pragma unroll
      for (int j = 0; j < 4; ++j) {
        float v = scb[4 * g + j];
        if (v > m1) { m2 = m1; m1 = v; } else if (v > m2) { m2 = v; }
      }
      gs[g] = m1 + m2;
    }
    int g1 = -1, g2 = -1;
    { float b = -1e30f; for (int g = 0; g < 4; ++g) if (gs[g] > b) { b = gs[g]; g1 = g; } }
    { float b = -1e30f; for (int g = 0; g < 4; ++g) if (g != g1 && gs[g] > b) { b = gs[g]; g2 = g; } }
    bool used[NEXP];
#pragma unroll
    for (int n = 0; n < NEXP; ++n) used[n] = false;
    int sel[4]; float wts[4]; float s = 0.f;
    for (int k = 0; k < 4; ++k) {
      float b = -1e30f; int bi = 0;
      for (int n = 0; n < NEXP; ++n) {
        int g = n >> 2;
        if ((g == g1 || g == g2) && !used[n] && scb[n] > b) { b = scb[n]; bi = n; }
      }
      used[bi] = true; sel[k] = bi; wts[k] = sc[bi]; s += sc[bi];
    }
    float inv = 2.5f / (s + 1e-20f);
    for (int k = 0; k < 4; ++k) {
      topk_idx[t * 4 + k] = sel[k];
      topk_w[t * 4 + k] = wts[k] * inv;
    }
  }
}

// ---------------- histogram + prefix in one small kernel (no atomics) ----------------
// 1 block x 256 thr; wave-ballot per expert; statically-indexed regs (rule #20).
__global__ __launch_bounds__(256) void count_prefix(const int* __restrict__ topki,
                                                    int* __restrict__ offs) {
  __shared__ int wsum[4][NEXP];
  int tid = threadIdx.x, lane = tid & 63, wv = tid >> 6;
  int c[NEXP];
#pragma unroll
  for (int e = 0; e < NEXP; ++e) c[e] = 0;
  for (int i0 = wv * 64; i0 < NTOK * 4; i0 += 256) {
    int v = topki[i0 + lane];
#pragma unroll
    for (int e = 0; e < NEXP; ++e) {
      unsigned long long b = __ballot(v == e);
      if (lane == 0) c[e] += __popcll(b);
    }
  }
  if (lane == 0) {
#pragma unroll
    for (int e = 0; e < NEXP; ++e) wsum[wv][e] = c[e];
  }
  __syncthreads();
  if (tid == 0) {
    int s = 0;
    for (int e = 0; e < NEXP; ++e) {
      int t = wsum[0][e] + wsum[1][e] + wsum[2][e] + wsum[3][e];
      offs[e] = s;
      s += t;
    }
    offs[NEXP] = s;
  }
}

// ---------------- deterministic ordered compaction + slot map ----------------
__global__ void fill_lists(const int* __restrict__ topk_idx,
                           const int* __restrict__ offs, int* __restrict__ ltok,
                           int* __restrict__ slotmap) {
  int e = blockIdx.x;
  int tid = threadIdx.x, lane = tid & 63, wv = tid >> 6;
  __shared__ int cursor;
  __shared__ int wcnt[4];
  if (tid == 0) cursor = offs[e];
  __syncthreads();
  for (int base = 0; base < NTOK; base += 256) {
    int t = base + tid;
    int flag = 0, kk = 0;
#pragma unroll
    for (int k = 0; k < 4; ++k) {
      if (topk_idx[t * 4 + k] == e) { flag = 1; kk = k; }
    }
    unsigned long long b = __ballot(flag);
    if (lane == 0) wcnt[wv] = __popcll(b);
    __syncthreads();
    int pre = 0;
    for (int i = 0; i < wv; ++i) pre += wcnt[i];
    int pos = cursor + pre + __popcll(b & ((1ull << lane) - 1ull));
    if (flag) { ltok[pos] = t; slotmap[t * 4 + kk] = pos; }
    __syncthreads();
    if (tid == 0) cursor += wcnt[0] + wcnt[1] + wcnt[2] + wcnt[3];
    __syncthreads();
  }
}

// ---------------- in-place paired silu ----------------
template <int F>
__global__ void silu_mul_pair(u16* __restrict__ gu, const int* __restrict__ nrows_ptr,
                              int nrows_static) {
  int rows = nrows_ptr ? *nrows_ptr : nrows_static;
  long total4 = (long)rows * (F / 4);
  long i = (long)blockIdx.x * blockDim.x + threadIdx.x;
  if (i < total4) {
    long row = i / (F / 4);
    int f4 = (int)(i - row * (F / 4));
    ushort4* rowp = (ushort4*)(gu + row * 2 * F);
    ushort4 gv = rowp[f4];
    ushort4 uv = rowp[F / 4 + f4];
    float gf, uf, sv;
    ushort4 o;
    gf = bf2f(gv.x); uf = bf2f(uv.x); sv = gf / (1.f + __expf(-gf)); o.x = f2bf(sv * uf);
    gf = bf2f(gv.y); uf = bf2f(uv.y); sv = gf / (1.f + __expf(-gf)); o.y = f2bf(sv * uf);
    gf = bf2f(gv.z); uf = bf2f(uv.z); sv = gf / (1.f + __expf(-gf)); o.z = f2bf(sv * uf);
    gf = bf2f(gv.w); uf = bf2f(uv.w); sv = gf / (1.f + __expf(-gf)); o.w = f2bf(sv * uf);
    rowp[f4] = o;
  }
}

// ---------------- final reduce ----------------
__global__ void reduce_out(const u16* __restrict__ SY, const u16* __restrict__ Y,
                           const int* __restrict__ slotmap, const float* __restrict__ tkw,
                           float* __restrict__ out) {
  long i = (long)blockIdx.x * blockDim.x + threadIdx.x;  // over NTOK*HDIM/4
  int t = (int)(i >> 9);       // HDIM/4 = 512
  int c4 = (int)(i & 511);
  ushort4 s = ((const ushort4*)SY)[i];
  float4 o;
  o.x = bf2f(s.x); o.y = bf2f(s.y); o.z = bf2f(s.z); o.w = bf2f(s.w);
#pragma unroll
  for (int k = 0; k < 4; ++k) {
    int sl = slotmap[t * 4 + k];
    float w = tkw[t * 4 + k];
    ushort4 y = ((const ushort4*)Y)[(long)sl * 512 + c4];
    o.x += w * bf2f(y.x);
    o.y += w * bf2f(y.y);
    o.z += w * bf2f(y.z);
    o.w += w * bf2f(y.w);
  }
  ((float4*)out)[i] = o;
}

// ================= 256x256 bf16 GEMM-BT, 8-phase counted-vmcnt schedule (v2) =================
// 512 thr = 8 waves (2M x 4N); per-wave 128x64 out; BK=64; 128 KiB LDS, 2 buffers.
// v2: phase->fragment mapping keeps fragment live set at 64 VGPR (no spill).
// Per K-tile quadrant order Q(0,lo) Q(0,hi) Q(4,hi) Q(4,lo); reads/phase: 12/4/8/0.
// LDS (u16 idx): buf p at p*32768; A rows linear at row*64; B at 16384 + row*64.
// Swizzle: col-chunk ^= (row&7) on global SOURCE + on ds_read addr (write side linear).
#define LGKM0 asm volatile("s_waitcnt lgkmcnt(0)" ::: "memory")
#define VMC4  asm volatile("s_waitcnt vmcnt(4)" ::: "memory")
#define VMC0  asm volatile("s_waitcnt vmcnt(0)" ::: "memory")
__device__ __forceinline__ void bar() {
  asm volatile("" ::: "memory");
  __builtin_amdgcn_s_barrier();
  asm volatile("" ::: "memory");
}

__global__ __launch_bounds__(512, 2) void gemm256(
    const u16* __restrict__ A, const u16* __restrict__ B, u16* __restrict__ C,
    const int* __restrict__ gather, const int* __restrict__ offs,
    int Mstatic, int N, int K, int lda, long Bstride) {
  int e = blockIdx.z;
  int seg0 = 0, segM = Mstatic;
  if (offs) { seg0 = offs[e]; segM = offs[e + 1] - seg0; }
  int mt = blockIdx.y, nt = blockIdx.x;
  if (mt * 256 >= segM) return;
  const u16* Be = B + (long)e * Bstride;

  __shared__ __align__(16) u16 sm[65536];  // 128 KiB -> 1 block/CU

  int tid = threadIdx.x;
  int lane = tid & 63;
  int wv = tid >> 6, wm = wv >> 2, wn = wv & 3;
  int c4 = lane & 15, r4 = lane >> 4;

  // ---- staging addressing: thread covers (row = j*64 + tid>>3, chunk = tid&7) of a half-tile
  int srow = tid >> 3, schunk = tid & 7;
  int sswz8 = (schunk ^ (srow & 7)) * 8;   // pre-swizzled source col chunk
  int sOff = srow * 64 + schunk * 8;       // linear LDS dest

  u32 aoff[2][2], boff[2][2];              // element offsets, (h, j)
#pragma unroll
  for (int h = 0; h < 2; ++h)
#pragma unroll
    for (int j = 0; j < 2; ++j) {
      int rit = h * 128 + j * 64 + srow;
      int rl = mt * 256 + rit;
      if (rl >= segM) rl = mt * 256;       // clamp (masked at store)
      int ridx = seg0 + rl;
      u32 arow = gather ? (u32)gather[ridx] : (u32)ridx;
      aoff[h][j] = arow * (u32)lda + (u32)sswz8;
      boff[h][j] = (u32)(nt * 256 + rit) * (u32)K + (u32)sswz8;
    }

  // ---- ds_read lane addressing (row&7 == lane&7 for all frags)
  int swzv = (lane & 7) * 8;
  int aRL0 = c4 * 64 + ((r4 * 8) ^ swzv);  // kk=0
  int aRL1 = aRL0 ^ 32;                    // kk=1
  int aB0 = wm * 8192, aB1 = 32768 + aB0;
  int bB0 = 16384 + wn * 4096, bB1 = 32768 + bB0;

  f32x4 acc[8][4];
  bf16x8 af[4][2], bLo[2][2], bHi[2][2];
#pragma unroll
  for (int i = 0; i < 8; ++i)
#pragma unroll
    for (int j = 0; j < 4; ++j) acc[i][j] = f32x4{0.f, 0.f, 0.f, 0.f};

#define READ_A8(BASE) do { _Pragma("unroll") \
  for (int mi = 0; mi < 4; ++mi) { \
    af[mi][0] = *(const bf16x8*)&sm[(BASE) + mi * 1024 + aRL0]; \
    af[mi][1] = *(const bf16x8*)&sm[(BASE) + mi * 1024 + aRL1]; \
  } } while (0)
#define READ_B4(BASE, BARR) do { _Pragma("unroll") \
  for (int ni = 0; ni < 2; ++ni) { \
    BARR[ni][0] = *(const bf16x8*)&sm[(BASE) + ni * 1024 + aRL0]; \
    BARR[ni][1] = *(const bf16x8*)&sm[(BASE) + ni * 1024 + aRL1]; \
  } } while (0)
#define MFMAQ(MI0, NI0, BARR) do { __builtin_amdgcn_s_setprio(1); \
  _Pragma("unroll") for (int mi = 0; mi < 4; ++mi) \
  _Pragma("unroll") for (int ni = 0; ni < 2; ++ni) \
  _Pragma("unroll") for (int kk = 0; kk < 2; ++kk) \
    acc[(MI0) + mi][(NI0) + ni] = __builtin_amdgcn_mfma_f32_16x16x32_bf16( \
        af[mi][kk], BARR[ni][kk], acc[(MI0) + mi][(NI0) + ni], 0, 0, 0); \
  __builtin_amdgcn_s_setprio(0); } while (0)
#define STAGE_A(PO, H, T) do { \
  gld_lds16(A + aoff[H][0] + (u32)((T) * 64), &sm[(PO) + (H) * 8192 + sOff]); \
  gld_lds16(A + aoff[H][1] + (u32)((T) * 64), &sm[(PO) + (H) * 8192 + 4096 + sOff]); \
} while (0)
#define STAGE_B(PO, H, T) do { \
  gld_lds16(Be + boff[H][0] + (u32)((T) * 64), &sm[(PO) + 16384 + (H) * 8192 + sOff]); \
  gld_lds16(Be + boff[H][1] + (u32)((T) * 64), &sm[(PO) + 16384 + (H) * 8192 + 4096 + sOff]); \
} while (0)

  // ---- prologue: tile0 (4 halves) + B of tile1 (2 halves); A of tile1 staged at ph1/ph2
  STAGE_A(0, 0, 0); STAGE_A(0, 1, 0); STAGE_B(0, 0, 0); STAGE_B(0, 1, 0);
  STAGE_B(32768, 0, 1); STAGE_B(32768, 1, 1);
  VMC4;   // tile0's 8 loads landed; Bod(1) outstanding
  bar();

  int niter = K >> 7;  // 2 K-tiles per iteration
  for (int it = 0; it < niter; ++it) {
    int to = 2 * it + 1, t2 = 2 * it + 2, t3 = 2 * it + 3;
    bool nl = (it + 1 < niter);
    // ph1: read a0-3(E) + bLo(E) (12 reads); stage Aod h0 (tile 2it+1)
    READ_A8(aB0); READ_B4(bB0, bLo);
    STAGE_A(32768, 0, to);
    bar(); LGKM0; MFMAQ(0, 0, bLo); bar();
    // ph2: read bHi(E) (4); stage Aod h1
    READ_B4(bB0 + 2048, bHi);
    STAGE_A(32768, 1, to);
    bar(); LGKM0; MFMAQ(0, 2, bHi); bar();
    // ph3: read a4-7(E) (8); stage Bev h0 (t2)  [Bev free after ph2]
    READ_A8(aB0 + 4096);
    if (nl) STAGE_B(0, 0, t2);
    bar(); LGKM0; MFMAQ(4, 2, bHi); bar();
    // ph4: no reads; stage Bev h1 (t2); counted vmcnt -> odd tile (2it+1) landed
    if (nl) { STAGE_B(0, 1, t2); VMC4; } else { VMC0; }
    bar(); MFMAQ(4, 0, bLo); bar();
    // ph5: read a0-3(O) + bLo(O); stage Aev h0 (t2)  [Aev free after ph3]
    READ_A8(aB1); READ_B4(bB1, bLo);
    if (nl) STAGE_A(0, 0, t2);
    bar(); LGKM0; MFMAQ(0, 0, bLo); bar();
    // ph6: read bHi(O); stage Aev h1 (t2)
    READ_B4(bB1 + 2048, bHi);
    if (nl) STAGE_A(0, 1, t2);
    bar(); LGKM0; MFMAQ(0, 2, bHi); bar();
    // ph7: read a4-7(O); stage Bod h0 (t3)  [Bod free after ph6]
    READ_A8(aB1 + 4096);
    if (nl) STAGE_B(32768, 0, t3);
    bar(); LGKM0; MFMAQ(4, 2, bHi); bar();
    // ph8: stage Bod h1 (t3); counted vmcnt -> even tile (t2) landed for next ph1
    if (nl) { STAGE_B(32768, 1, t3); VMC4; }
    bar(); MFMAQ(4, 0, bLo); bar();
  }

#undef READ_A8
#undef READ_B4
#undef MFMAQ
#undef STAGE_A
#undef STAGE_B

  // ---- epilogue: C/D layout col=lane&15, row=(lane>>4)*4+reg (m89-verified)
#pragma unroll
  for (int mi = 0; mi < 8; ++mi) {
#pragma unroll
    for (int r = 0; r < 4; ++r) {
      int lr = wm * 128 + mi * 16 + r4 * 4 + r;
      if (mt * 256 + lr < segM) {
        long base = (long)(seg0 + mt * 256 + lr) * N + nt * 256 + wn * 64 + c4;
#pragma unroll
        for (int ni = 0; ni < 4; ++ni) C[base + ni * 16] = f2bf(acc[mi][ni][r]);
      }
    }
  }
}

extern "C" void kernel_launch(void* const* d_in, const int* in_sizes, int n_in,
                              void* d_out, int out_size, void* d_ws, size_t ws_size,
                              hipStream_t stream) {
  const float* hidden = (const float*)d_in[0];       // [4096, 2048]
  const float* gate_weight = (const float*)d_in[1];  // [16, 2048]
  const float* bias = (const float*)d_in[2];         // [16]
  const float* gate_w = (const float*)d_in[3];       // [16, 1024, 2048]
  const float* up_w = (const float*)d_in[4];         // [16, 1024, 2048]
  const float* down_w = (const float*)d_in[5];       // [16, 2048, 1024]
  const float* shg = (const float*)d_in[6];          // [2048, 2048]
  const float* shu = (const float*)d_in[7];          // [2048, 2048]
  const float* shd = (const float*)d_in[8];          // [2048, 2048]
  float* out = (float*)d_out;                        // [4096, 2048]

  char* p = (char*)d_ws;
  auto alloc = [&](size_t bytes) {
    char* q = p;
    p += (bytes + 255) & ~(size_t)255;
    return q;
  };
  u16* Xb = (u16*)alloc((size_t)NTOK * HDIM * 2);                 // 16 MB bf16 hidden
  u16* GUb = (u16*)alloc((size_t)NEXP * 2 * FMOE * HDIM * 2);     // 128 MB [e][gate;up]
  u16* Db = (u16*)alloc((size_t)NEXP * HDIM * FMOE * 2);          // 64 MB
  u16* SGUb = (u16*)alloc((size_t)2 * FSH * HDIM * 2);            // 16 MB [gate;up]
  u16* SDb = (u16*)alloc((size_t)HDIM * FSH * 2);                 // 8 MB
  u16* gu_out = (u16*)alloc((size_t)NTOK * 4 * 2 * FMOE * 2);     // 64 MB routed gate|up
  int* topki = (int*)alloc((size_t)NTOK * 4 * 4);
  float* topkw = (float*)alloc((size_t)NTOK * 4 * 4);
  int* offs = (int*)alloc(128);
  int* ltok = (int*)alloc((size_t)NTOK * 4 * 4);
  int* slotmap = (int*)alloc((size_t)NTOK * 4 * 4);
  // aliases into GUb, valid AFTER the routed gate/up GEMM consumed the weights:
  u16* Y = GUb;                                                   // 64 MB routed down out
  u16* gs_out = GUb + (size_t)NTOK * 4 * HDIM;                    // 32 MB shared gate|up
  u16* SY = gs_out + (size_t)NTOK * 2 * FSH;                      // 16 MB shared down out

  // fp32 -> bf16 conversions
  cvt_bf16<<<8192, 256, 0, stream>>>(hidden, Xb, (long)NTOK * HDIM / 4);
  cvt_pair_moe<<<dim3(2048, 1, NEXP), 256, 0, stream>>>(gate_w, up_w, GUb);
  cvt_bf16<<<32768, 256, 0, stream>>>(down_w, Db, (long)NEXP * HDIM * FMOE / 4);
  cvt_bf16<<<4096, 256, 0, stream>>>(shg, SGUb, (long)FSH * HDIM / 4);
  cvt_bf16<<<4096, 256, 0, stream>>>(shu, SGUb + (size_t)FSH * HDIM, (long)FSH * HDIM / 4);
  cvt_bf16<<<4096, 256, 0, stream>>>(shd, SDb, (long)HDIM * FSH / 4);

  // routing + expert lists (atomic-free)
  routing_kernel<<<NTOK / 4, 256, 0, stream>>>(hidden, gate_weight, bias, topki, topkw);
  count_prefix<<<1, 256, 0, stream>>>(topki, offs);
  fill_lists<<<NEXP, 256, 0, stream>>>(topki, offs, ltok, slotmap);

  // routed fused gate+up GEMM: [rows x 2048] = X(gathered) @ GU[e]^T, then in-place silu
  gemm256<<<dim3(2 * FMOE / 256, NTOK / 256, NEXP), 512, 0, stream>>>(
      Xb, GUb, gu_out, ltok, offs, 0, 2 * FMOE, HDIM, HDIM, (long)2 * FMOE * HDIM);
  silu_mul_pair<FMOE><<<16384, 256, 0, stream>>>(gu_out, offs + NEXP, 0);
  // routed down: [rows x 2048] = act @ D[e]^T, bf16 store in list order
  gemm256<<<dim3(HDIM / 256, NTOK / 256, NEXP), 512, 0, stream>>>(
      gu_out, Db, Y, nullptr, offs, 0, HDIM, FMOE, 2 * FMOE, (long)HDIM * FMOE);

  // shared expert: fused gate+up, silu, down
  gemm256<<<dim3(2 * FSH / 256, NTOK / 256, 1), 512, 0, stream>>>(
      Xb, SGUb, gs_out, nullptr, nullptr, NTOK, 2 * FSH, HDIM, HDIM, 0);
  silu_mul_pair<FSH><<<8192, 256, 0, stream>>>(gs_out, nullptr, NTOK);
  gemm256<<<dim3(HDIM / 256, NTOK / 256, 1), 512, 0, stream>>>(
      gs_out, SDb, SY, nullptr, nullptr, NTOK, HDIM, FSH, 2 * FSH, 0);

  // final: out[t] = SY[t] + sum_k w * Y[slot]
  reduce_out<<<8192, 256, 0, stream>>>(SY, Y, slotmap, topkw, out);
}